// Round 8
// baseline (2644.876 us; speedup 1.0000x reference)
//
#include <hip/hip_runtime.h>
#include <hip/hip_bf16.h>

// ---------------------------------------------------------------------------
// InvSlotAttentionGuide: CNN encoder -> pos embed -> MLP -> slot attention
// with MESH-Sinkhorn (manual reverse-mode through 5 sinkhorn iters).
// f32 end-to-end. R8: sa_kernel widened to 1024 threads (1 row/thread; row
// phases 2x), __expf/__logf fast transcendentals (libm exp/log were the
// dominant VALU cost), sUpd matmul split+combine. Conv/token kept from R7.
// ---------------------------------------------------------------------------

#define LN_EPS 1e-5f
#define SEPS 1e-8f
#define LN8 2.0794415416798357f

__device__ inline float wmaxall(float v) {
#pragma unroll
  for (int o = 32; o; o >>= 1) v = fmaxf(v, __shfl_down(v, o));
  return __shfl(v, 0);
}
__device__ inline float wsumall(float v) {
#pragma unroll
  for (int o = 32; o; o >>= 1) v += __shfl_down(v, o);
  return __shfl(v, 0);
}
__device__ inline int wsumi(int v) {
#pragma unroll
  for (int o = 32; o; o >>= 1) v += __shfl_down(v, o);
  return __shfl(v, 0);
}

// ---------------------------------------------------------------------------
__global__ __launch_bounds__(64) void sniff_kernel(const unsigned int* __restrict__ img,
                                                   int* __restrict__ flag) {
  int cnt = 0;
  for (int i = threadIdx.x; i < 512; i += 64) {
    unsigned lo = img[i] & 0xFFFFu;
    int e = (int)((lo >> 7) & 0xFFu);
    cnt += (e >= 96 && e <= 140) ? 1 : 0;
  }
  cnt = wsumi(cnt);
  if (threadIdx.x == 0) *flag = (cnt >= 300) ? 1 : 0;
}

struct CvtArgs {
  const void* src[39];
  long off[40];
};

__global__ __launch_bounds__(256) void convert_kernel(CvtArgs a, const int* __restrict__ flag,
                                                      float* __restrict__ dst, long total) {
  const int isbf = *flag;
  for (long g = (long)blockIdx.x * 256 + threadIdx.x; g < total; g += (long)gridDim.x * 256) {
    int lo = 0, hi = 38;
    while (lo < hi) {
      int mid = (lo + hi + 1) >> 1;
      if (a.off[mid] <= g) lo = mid; else hi = mid - 1;
    }
    long li = g - a.off[lo];
    float v;
    if (isbf) v = __bfloat162float(((const __hip_bfloat16*)a.src[lo])[li]);
    else      v = ((const float*)a.src[lo])[li];
    dst[g] = v;
  }
}

// ---------------------------------------------------------------------------
struct TwArgs {
  long soff[9]; long doff[9]; int R[9]; int C[9];
};

__global__ __launch_bounds__(256) void transw_kernel(const float* __restrict__ cvt,
                                                     float* __restrict__ tws, TwArgs a) {
  int m = blockIdx.x;
  const float* S = cvt + a.soff[m];
  float* D = tws + a.doff[m];
  int R = a.R[m], C = a.C[m];
  for (int idx = threadIdx.x; idx < R * C; idx += 256) {
    int i = idx / C, j = idx - i * C;
    D[j * R + i] = S[idx];
  }
}

// ---------------------------------------------------------------------------
// Direct 5x5 conv + bias + relu (R7-verified): 16x16 tile, 16 oc/block,
// 2x2-px x 4-oc micro-tile, weights LDS-staged.
// ---------------------------------------------------------------------------
template <int S>
__global__ __launch_bounds__(256) void conv5x5(
    const float* __restrict__ in, const float* __restrict__ wgt,
    const float* __restrict__ bias, float* __restrict__ out,
    int Cin, int H, int W, int Wo, int Cout, int tilesX,
    int oybeg, int oyend, int ibase, int irows, int obase, int orows) {
  constexpr int P = 15 * S + 5;
  __shared__ float patch[P * P];
  __shared__ float wt[16 * 25];
  const int b = blockIdx.z;
  const int ocg = blockIdx.y * 16;
  const int ty0 = oybeg + (blockIdx.x / tilesX) * 16, tx0 = (blockIdx.x % tilesX) * 16;
  const int og = threadIdx.x >> 6;
  const int q = threadIdx.x & 63;
  const int qx = q & 7, qy = q >> 3;
  const int iy0 = ty0 * S - 2, ix0 = tx0 * S - 2;
  float acc[2][2][4];
#pragma unroll
  for (int dy = 0; dy < 2; dy++)
#pragma unroll
    for (int dx = 0; dx < 2; dx++)
#pragma unroll
      for (int j = 0; j < 4; j++) acc[dy][dx][j] = 0.f;

  for (int ci = 0; ci < Cin; ++ci) {
    const float* inp = in + ((long)b * Cin + ci) * (long)irows * W;
    for (int idx = threadIdx.x; idx < P * P; idx += 256) {
      int py = idx / P, px = idx - py * P;
      int iy = iy0 + py, ix = ix0 + px;
      float v = 0.f;
      if (iy >= 0 && iy < H && ix >= 0 && ix < W) v = inp[(long)(iy - ibase) * W + ix];
      patch[idx] = v;
    }
    for (int idx = threadIdx.x; idx < 16 * 25; idx += 256) {
      int j = idx / 25, tp = idx - j * 25;
      wt[idx] = wgt[((long)(ocg + j) * Cin + ci) * 25 + tp];
    }
    __syncthreads();
#pragma unroll
    for (int ky = 0; ky < 5; ky++) {
#pragma unroll
      for (int kx = 0; kx < 5; kx++) {
        const int wof = ky * 5 + kx;
        float w0 = wt[(og * 4 + 0) * 25 + wof];
        float w1 = wt[(og * 4 + 1) * 25 + wof];
        float w2 = wt[(og * 4 + 2) * 25 + wof];
        float w3 = wt[(og * 4 + 3) * 25 + wof];
#pragma unroll
        for (int dy = 0; dy < 2; dy++) {
#pragma unroll
          for (int dx = 0; dx < 2; dx++) {
            float iv = patch[((qy + 8 * dy) * S + ky) * P + (qx + 8 * dx) * S + kx];
            acc[dy][dx][0] += iv * w0;
            acc[dy][dx][1] += iv * w1;
            acc[dy][dx][2] += iv * w2;
            acc[dy][dx][3] += iv * w3;
          }
        }
      }
    }
    __syncthreads();
  }
#pragma unroll
  for (int dy = 0; dy < 2; dy++) {
    int oy = ty0 + qy + 8 * dy;
    if (oy >= oyend) continue;
#pragma unroll
    for (int dx = 0; dx < 2; dx++) {
      int ox = tx0 + qx + 8 * dx;
#pragma unroll
      for (int j = 0; j < 4; j++) {
        int oc = ocg + og * 4 + j;
        float r = fmaxf(acc[dy][dx][j] + bias[oc], 0.f);
        out[(((long)b * Cout + oc) * orows + (oy - obase)) * Wo + ox] = r;
      }
    }
  }
}

// ---------------------------------------------------------------------------
__global__ __launch_bounds__(256) void posembed_kernel(
    const float* __restrict__ act4, const float* __restrict__ pos_w,
    const float* __restrict__ pos_b, float* __restrict__ feat) {
  int idx = blockIdx.x * 256 + threadIdx.x;
  if (idx >= 16 * 1024 * 64) return;
  int c = idx & 63;
  int n = (idx >> 6) & 1023;
  int b = idx >> 16;
  int h = n >> 5, w = n & 31;
  float gh = h * (1.f / 31.f), gw = w * (1.f / 31.f);
  float e = gh * pos_w[c * 4 + 0] + gw * pos_w[c * 4 + 1] +
            (1.f - gh) * pos_w[c * 4 + 2] + (1.f - gw) * pos_w[c * 4 + 3] + pos_b[c];
  feat[idx] = act4[(((long)b * 64 + c) * 32 + h) * 32 + w] + e;
}

// ---------------------------------------------------------------------------
__global__ __launch_bounds__(64) void token_kernel(
    const float* __restrict__ feat,
    const float* __restrict__ mlp1T, const float* __restrict__ mlp1_b,
    const float* __restrict__ mlp2T, const float* __restrict__ mlp2_b,
    const float* __restrict__ lnin_w, const float* __restrict__ lnin_b,
    const float* __restrict__ wkT, const float* __restrict__ wvT,
    const float* __restrict__ mwi_w, const float* __restrict__ mwi_b,
    float* __restrict__ knT_out, float* __restrict__ v_out, float* __restrict__ lg_out) {
  const int t = blockIdx.x, i = threadIdx.x;
  const int b = t >> 10, nn = t & 1023;
  __shared__ float f[64], h1[64], inp[64];
  f[i] = feat[(long)t * 64 + i];
  __syncthreads();
  float acc = 0.f;
  for (int j = 0; j < 64; j++) acc += f[j] * mlp1T[j * 64 + i];
  h1[i] = fmaxf(acc + mlp1_b[i], 0.f);
  __syncthreads();
  acc = 0.f;
  for (int j = 0; j < 64; j++) acc += h1[j] * mlp2T[j * 64 + i];
  float x = acc + mlp2_b[i];
  float m = wsumall(x) * (1.f / 64.f);
  float d0 = x - m;
  float var = wsumall(d0 * d0) * (1.f / 64.f);
  float xin = d0 * rsqrtf(var + LN_EPS) * lnin_w[i] + lnin_b[i];
  inp[i] = xin;
  __syncthreads();
  float kv = 0.f, vv = 0.f;
  for (int j = 0; j < 64; j++) {
    float ij = inp[j];
    kv += ij * wkT[j * 64 + i];
    vv += ij * wvT[j * 64 + i];
  }
  float ss = wsumall(kv * kv);
  knT_out[(long)b * 65536 + i * 1024 + nn] = kv / fmaxf(sqrtf(ss), 1e-12f);
  v_out[(long)t * 64 + i] = vv;
  float lg = wsumall(xin * mwi_w[i]);
  if (i == 0) lg_out[t] = lg + mwi_b[0];
}

// ---------------------------------------------------------------------------
__global__ __launch_bounds__(256) void la_kernel(float* __restrict__ lg) {
  __shared__ float red[256];
  const int b = blockIdx.x, t = threadIdx.x;
  float* p = lg + b * 1024;
  float mx = -1e30f;
  for (int n = t; n < 1024; n += 256) mx = fmaxf(mx, p[n]);
  red[t] = mx;
  __syncthreads();
  for (int o = 128; o; o >>= 1) {
    if (t < o) red[t] = fmaxf(red[t], red[t + o]);
    __syncthreads();
  }
  float M = red[0];
  __syncthreads();
  float s = 0.f;
  for (int n = t; n < 1024; n += 256) s += __expf(p[n] - M);
  red[t] = s;
  __syncthreads();
  for (int o = 128; o; o >>= 1) {
    if (t < o) red[t] += red[t + o];
    __syncthreads();
  }
  float lse = M + __logf(red[0]);
  __syncthreads();
  for (int n = t; n < 1024; n += 256) p[n] = p[n] - lse + LN8;
}

// ---------------------------------------------------------------------------
// Slot-attention loop: 1 block/batch, 1024 threads = 16 waves.
// Row phases: 1 row/thread. Column phases: 8 waves (wave s = column s),
// waves 8..15 idle there. gP & u-history in registers. Fast __expf/__logf.
// ---------------------------------------------------------------------------
__global__ __launch_bounds__(1024) void sa_kernel(
    const float* __restrict__ knT_g, const float* __restrict__ v_g,
    const float* __restrict__ la_g, const float* __restrict__ noise,
    const float* __restrict__ mu_w, const float* __restrict__ sg_w,
    const float* __restrict__ lnsl_w, const float* __restrict__ lnsl_b,
    const float* __restrict__ mws_w, const float* __restrict__ mws_b,
    const float* __restrict__ wqT,
    const float* __restrict__ wihT, const float* __restrict__ whhT,
    const float* __restrict__ bih, const float* __restrict__ bhh,
    const float* __restrict__ lnff_w, const float* __restrict__ lnff_b,
    const float* __restrict__ fc1T, const float* __restrict__ fc1_b,
    const float* __restrict__ fc2T, const float* __restrict__ fc2_b,
    float* __restrict__ out) {
  const int b = blockIdx.x, tid = threadIdx.x;
  const int wv = tid >> 6, ln = tid & 63;

  __shared__ float sCt[8192];                                    // C^T (then pi^T)
  __shared__ float sLa[1024], sU[1024], sGu[1024], sRow[1024];
  __shared__ float sUpdP[1024], sHid[1024];
  __shared__ float sVh[48], sV[8], sGv[8], sLb[8], sCol[8], sBm[8];
  __shared__ float sSlots[512], sNorm[512], sQn[512], sUpd[512];

  const float* knt = knT_g + (long)b * 65536;  // [64][1024]
  const float* vf = v_g + (long)b * 65536;     // [1024][64]
  float u_hist[5];   // u_t for my row, t=1..5
  float gPr[8];      // grad wrt p for my row

  if (tid < 512) {
    int dd = tid & 63;
    sSlots[tid] = mu_w[dd] + (fabsf(sg_w[dd]) + SEPS) * noise[(long)b * 512 + tid];
  }
  sLa[tid] = la_g[b * 1024 + tid];
  __syncthreads();

  for (int it = 0; it < 3; ++it) {
    if (tid < 512) {  // slot LN + bm logit (wave wv = slot wv, wv<8)
      float x = sSlots[wv * 64 + ln];
      float m = wsumall(x) * (1.f / 64.f);
      float d0 = x - m;
      float var = wsumall(d0 * d0) * (1.f / 64.f);
      float xn = d0 * rsqrtf(var + LN_EPS) * lnsl_w[ln] + lnsl_b[ln];
      sNorm[wv * 64 + ln] = xn;
      float bmv = wsumall(xn * mws_w[ln]);
      if (ln == 0) sBm[wv] = bmv + mws_b[0];
    }
    __syncthreads();
    if (tid == 0) {
      float mx = -1e30f;
      for (int s = 0; s < 8; s++) mx = fmaxf(mx, sBm[s]);
      float ss = 0.f;
      for (int s = 0; s < 8; s++) ss += __expf(sBm[s] - mx);
      float lse = mx + __logf(ss);
      for (int s = 0; s < 8; s++) sLb[s] = sBm[s] - lse + LN8;
    }
    if (tid < 512) {  // q = sNorm @ wq.T
      float acc = 0.f;
      for (int j = 0; j < 64; j++) acc += sNorm[wv * 64 + j] * wqT[j * 64 + ln];
      sQn[tid] = acc;
    }
    __syncthreads();
    if (tid < 512) {  // l2norm q
      float qv = sQn[wv * 64 + ln];
      float ss = wsumall(qv * qv);
      sQn[wv * 64 + ln] = qv / fmaxf(sqrtf(ss), 1e-12f);
    }
    if (tid < 8) sV[tid] = 0.f;
    __syncthreads();

    {  // C^T = 1 - qn . kn  (1 row/thread)
      int n = tid;
      float acc[8];
#pragma unroll
      for (int s = 0; s < 8; s++) acc[s] = 0.f;
      for (int j = 0; j < 64; j++) {
        float kvv = knt[j * 1024 + n];
#pragma unroll
        for (int s = 0; s < 8; s++) acc[s] += kvv * sQn[s * 64 + j];
      }
#pragma unroll
      for (int s = 0; s < 8; s++) sCt[s * 1024 + n] = 1.f - acc[s];
    }
    __syncthreads();

    // --- MESH: 4 x (fwd 5 sinkhorn, entropy-grad bwd, C += gP) ---
    for (int m = 0; m < 4; m++) {
      if (tid < 8) sVh[tid] = sV[tid];
      __syncthreads();
#pragma unroll
      for (int t = 1; t <= 5; t++) {
        {  // row LSE -> u
          int n = tid;
          float mx = -1e30f;
#pragma unroll
          for (int s = 0; s < 8; s++) mx = fmaxf(mx, sV[s] - sCt[s * 1024 + n]);
          float ssum = 0.f;
#pragma unroll
          for (int s = 0; s < 8; s++) ssum += __expf(sV[s] - sCt[s * 1024 + n] - mx);
          float un = sLa[n] - (mx + __logf(ssum));
          sU[n] = un;
          u_hist[t - 1] = un;
        }
        __syncthreads();
        if (wv < 8) {  // col LSE -> v
          int s = wv;
          float mx = -1e30f;
          for (int n = ln; n < 1024; n += 64) mx = fmaxf(mx, sU[n] - sCt[s * 1024 + n]);
          mx = wmaxall(mx);
          float ssum = 0.f;
          for (int n = ln; n < 1024; n += 64) ssum += __expf(sU[n] - sCt[s * 1024 + n] - mx);
          ssum = wsumall(ssum);
          if (ln == 0) {
            float vs = sLb[s] - (mx + __logf(ssum));
            sV[s] = vs;
            sVh[t * 8 + s] = vs;
          }
        }
        __syncthreads();
      }
      {  // backward init: entropy grad rows
        int n = tid;
        float un = u_hist[4];
        float gul = 0.f;
#pragma unroll
        for (int s = 0; s < 8; s++) {
          float pi = __expf(un + sV[s] - sCt[s * 1024 + n]);
          float gl = -(__logf(pi + SEPS) + pi / (pi + SEPS)) * pi * (1.f / 16.f);
          gPr[s] = gl;
          gul += gl;
        }
        sGu[n] = gul;
      }
      __syncthreads();
      if (wv < 8) {  // gv col sums (sU holds u5)
        int s = wv;
        float vs = sV[s];
        float acc = 0.f;
        for (int n = ln; n < 1024; n += 64) {
          float pi = __expf(sU[n] + vs - sCt[s * 1024 + n]);
          acc += -(__logf(pi + SEPS) + pi / (pi + SEPS)) * pi * (1.f / 16.f);
        }
        acc = wsumall(acc);
        if (ln == 0) sGv[s] = acc;
      }
      __syncthreads();
#pragma unroll
      for (int t = 5; t >= 1; t--) {
        if (wv < 8) {  // column LSE of (u_t - C)
          int s = wv;
          float mx = -1e30f;
          for (int n = ln; n < 1024; n += 64) mx = fmaxf(mx, sU[n] - sCt[s * 1024 + n]);
          mx = wmaxall(mx);
          float ssum = 0.f;
          for (int n = ln; n < 1024; n += 64) ssum += __expf(sU[n] - sCt[s * 1024 + n] - mx);
          ssum = wsumall(ssum);
          if (ln == 0) sCol[s] = mx + __logf(ssum);
        }
        __syncthreads();
        {  // sigma row pass
          int n = tid;
          float un = u_hist[t - 1];
          float gul = (t == 5) ? sGu[n] : 0.f;
#pragma unroll
          for (int s = 0; s < 8; s++) {
            float t2 = sGv[s] * __expf(un - sCt[s * 1024 + n] - sCol[s]);
            gPr[s] -= t2;
            gul -= t2;
          }
          sGu[n] = gul;
        }
        __syncthreads();
        {  // tau row pass (+ prep sU for next level)
          int n = tid;
          float mx = -1e30f;
#pragma unroll
          for (int s = 0; s < 8; s++) mx = fmaxf(mx, sVh[(t - 1) * 8 + s] - sCt[s * 1024 + n]);
          float ssum = 0.f;
#pragma unroll
          for (int s = 0; s < 8; s++) ssum += __expf(sVh[(t - 1) * 8 + s] - sCt[s * 1024 + n] - mx);
          float lse = mx + __logf(ssum);
          sRow[n] = lse;
          float gun = sGu[n];
#pragma unroll
          for (int s = 0; s < 8; s++)
            gPr[s] -= gun * __expf(sVh[(t - 1) * 8 + s] - sCt[s * 1024 + n] - lse);
          if (t > 1) sU[n] = u_hist[t - 2];
        }
        __syncthreads();
        if (t > 1) {
          if (wv < 8) {  // gv for v_{t-1}
            int s = wv;
            float vvh = sVh[(t - 1) * 8 + s];
            float acc = 0.f;
            for (int n = ln; n < 1024; n += 64)
              acc += sGu[n] * __expf(vvh - sCt[s * 1024 + n] - sRow[n]);
            acc = wsumall(acc);
            if (ln == 0) sGv[s] = -acc;
          }
          __syncthreads();
        }
      }
      if (tid < 8) sV[tid] = sVh[40 + tid];
      {  // C += gP
        int n = tid;
#pragma unroll
        for (int s = 0; s < 8; s++) sCt[s * 1024 + n] += gPr[s];
      }
      __syncthreads();
    }

    // --- final sinkhorn (5 iters, warm start v) ---
    for (int t = 0; t < 5; t++) {
      {
        int n = tid;
        float mx = -1e30f;
#pragma unroll
        for (int s = 0; s < 8; s++) mx = fmaxf(mx, sV[s] - sCt[s * 1024 + n]);
        float ssum = 0.f;
#pragma unroll
        for (int s = 0; s < 8; s++) ssum += __expf(sV[s] - sCt[s * 1024 + n] - mx);
        sU[n] = sLa[n] - (mx + __logf(ssum));
      }
      __syncthreads();
      if (wv < 8) {
        int s = wv;
        float mx = -1e30f;
        for (int n = ln; n < 1024; n += 64) mx = fmaxf(mx, sU[n] - sCt[s * 1024 + n]);
        mx = wmaxall(mx);
        float ssum = 0.f;
        for (int n = ln; n < 1024; n += 64) ssum += __expf(sU[n] - sCt[s * 1024 + n] - mx);
        ssum = wsumall(ssum);
        if (ln == 0) sV[s] = sLb[s] - (mx + __logf(ssum));
      }
      __syncthreads();
    }
    {  // pi^T in place of C^T
      int n = tid;
      float un = sU[n];
#pragma unroll
      for (int s = 0; s < 8; s++) sCt[s * 1024 + n] = __expf(un + sV[s] - sCt[s * 1024 + n]);
    }
    __syncthreads();
    if (it == 2) {
      for (int o = tid; o < 8192; o += 1024) out[8192 + (long)b * 8192 + o] = sCt[o];
    }
    {  // updates[s,d] = sum_n pi[n,s]*v[n,d], split over 2 half-ranges
      int h = tid >> 9, s = (tid >> 6) & 7, dd = tid & 63;
      float acc = 0.f;
      for (int n = h * 512; n < h * 512 + 512; n++)
        acc += sCt[s * 1024 + n] * vf[n * 64 + dd];
      sUpdP[tid] = acc;
    }
    __syncthreads();
    if (tid < 512) sUpd[tid] = sUpdP[tid] + sUpdP[tid + 512];
    __syncthreads();
    // --- GRU ---
    float newslot = 0.f;
    if (tid < 512) {
      int s = tid >> 6, i = tid & 63;
      const float* x = &sUpd[s * 64];
      const float* h = &sSlots[s * 64];
      float gir = 0, giz = 0, gin = 0, ghr = 0, ghz = 0, ghn = 0;
      for (int j = 0; j < 64; j++) {
        float xv = x[j], hv = h[j];
        gir += xv * wihT[j * 192 + i];
        giz += xv * wihT[j * 192 + 64 + i];
        gin += xv * wihT[j * 192 + 128 + i];
        ghr += hv * whhT[j * 192 + i];
        ghz += hv * whhT[j * 192 + 64 + i];
        ghn += hv * whhT[j * 192 + 128 + i];
      }
      gir += bih[i]; giz += bih[64 + i]; gin += bih[128 + i];
      ghr += bhh[i]; ghz += bhh[64 + i]; ghn += bhh[128 + i];
      float r = 1.f / (1.f + __expf(-(gir + ghr)));
      float z = 1.f / (1.f + __expf(-(giz + ghz)));
      float nn = tanhf(gin + r * ghn);
      newslot = (1.f - z) * nn + z * h[i];
    }
    __syncthreads();
    if (tid < 512) sSlots[tid] = newslot;
    __syncthreads();
    if (tid < 512) {  // ln_ff
      float x = sSlots[wv * 64 + ln];
      float m = wsumall(x) * (1.f / 64.f);
      float d0 = x - m;
      float var = wsumall(d0 * d0) * (1.f / 64.f);
      sNorm[wv * 64 + ln] = d0 * rsqrtf(var + LN_EPS) * lnff_w[ln] + lnff_b[ln];
    }
    __syncthreads();
    {  // fc1 (1024 outputs, 1/thread)
      int s = tid >> 7, k2 = tid & 127;
      float acc = 0.f;
      for (int j = 0; j < 64; j++) acc += sNorm[s * 64 + j] * fc1T[j * 128 + k2];
      sHid[tid] = fmaxf(acc + fc1_b[k2], 0.f);
    }
    __syncthreads();
    if (tid < 512) {  // fc2 + residual
      int s = tid >> 6, i = tid & 63;
      float acc = 0.f;
      for (int j = 0; j < 128; j++) acc += sHid[s * 128 + j] * fc2T[j * 64 + i];
      newslot = sSlots[tid] + acc + fc2_b[i];
    }
    __syncthreads();
    if (tid < 512) sSlots[tid] = newslot;
    __syncthreads();
  }
  if (tid < 512) out[(long)b * 512 + tid] = sSlots[tid];
}

// ---------------------------------------------------------------------------
extern "C" void kernel_launch(void* const* d_in, const int* in_sizes, int n_in,
                              void* d_out, int out_size, void* d_ws, size_t ws_size,
                              hipStream_t stream) {
  (void)n_in; (void)out_size; (void)ws_size;
  char* ws = (char*)d_ws;
  float* cvt  = (float*)ws;                     // converted f32 inputs (4.7 MB)
  float* lgts = (float*)(ws + 5570560ull);
  float* band = (float*)(ws + 5636096ull);      // conv1 row-band (18.9 MB)
  float* act2 = (float*)(ws + 24510464ull);     // (16.8 MB)
  float* act3 = (float*)(ws + 5636096ull);      // over dead band
  float* act4 = (float*)(ws + 9830400ull);
  float* knT  = (float*)(ws + 9830400ull);      // over dead act4 (4 MB)
  float* vf   = (float*)(ws + 14024704ull);
  float* feat = (float*)(ws + 24510464ull);     // over dead act2
  int*   flag = (int*)(ws + 41287680ull);
  float* tws  = (float*)(ws + 41291776ull);     // transposed weights (240 KB)

  CvtArgs ca;
  long total = 0;
  for (int i = 0; i < 39; i++) { ca.src[i] = d_in[i]; ca.off[i] = total; total += in_sizes[i]; }
  ca.off[39] = total;

  sniff_kernel<<<1, 64, 0, stream>>>((const unsigned int*)d_in[0], flag);
  convert_kernel<<<1024, 256, 0, stream>>>(ca, flag, cvt, total);

#define ARR(i) (cvt + ca.off[i])
  TwArgs ta;
  {
    const int src[9] = {12, 14, 18, 19, 20, 27, 28, 33, 35};
    const int R[9] = {64, 64, 64, 64, 64, 192, 192, 128, 64};
    const int C[9] = {64, 64, 64, 64, 64, 64, 64, 64, 128};
    long d = 0;
    for (int m2 = 0; m2 < 9; m2++) {
      ta.soff[m2] = ca.off[src[m2]];
      ta.doff[m2] = d;
      ta.R[m2] = R[m2];
      ta.C[m2] = C[m2];
      d += (long)R[m2] * C[m2];
    }
  }
  transw_kernel<<<9, 256, 0, stream>>>(cvt, tws, ta);
  float* mlp1T = tws + 0,     *mlp2T = tws + 4096,  *wkT = tws + 8192, *wvT = tws + 12288;
  float* wqT   = tws + 16384, *wihT  = tws + 20480, *whhT = tws + 32768;
  float* fc1T  = tws + 45056, *fc2T  = tws + 53248;

  const float* image = ARR(0);
  const float* noise = ARR(1);

  for (int q = 0; q < 4; q++) {
    int obase = (q == 0) ? 0 : 32 * q - 2;
    int oyend1 = (q == 3) ? 128 : 32 * q + 34;
    conv5x5<1><<<dim3(24, 4, 16), 256, 0, stream>>>(
        image, ARR(2), ARR(3), band, 3, 128, 128, 128, 64, 8,
        obase, oyend1, 0, 128, obase, 36);
    conv5x5<2><<<dim3(4, 4, 16), 256, 0, stream>>>(
        band, ARR(4), ARR(5), act2, 64, 128, 128, 64, 64, 4,
        16 * q, 16 * q + 16, obase, 36, 0, 64);
  }
  conv5x5<2><<<dim3(4, 4, 16), 256, 0, stream>>>(
      act2, ARR(6), ARR(7), act3, 64, 64, 64, 32, 64, 2, 0, 32, 0, 64, 0, 32);
  conv5x5<1><<<dim3(4, 4, 16), 256, 0, stream>>>(
      act3, ARR(8), ARR(9), act4, 64, 32, 32, 32, 64, 2, 0, 32, 0, 32, 0, 32);

  posembed_kernel<<<4096, 256, 0, stream>>>(act4, ARR(10), ARR(11), feat);

  token_kernel<<<16384, 64, 0, stream>>>(feat, mlp1T, ARR(13), mlp2T, ARR(15),
                                         ARR(16), ARR(17), wkT, wvT, ARR(21), ARR(22),
                                         knT, vf, lgts);

  la_kernel<<<16, 256, 0, stream>>>(lgts);

  sa_kernel<<<16, 1024, 0, stream>>>(knT, vf, lgts, noise, ARR(37), ARR(38),
                                     ARR(25), ARR(26), ARR(23), ARR(24), wqT,
                                     wihT, whhT, ARR(29), ARR(30),
                                     ARR(31), ARR(32), fc1T, ARR(34), fc2T, ARR(36),
                                     (float*)d_out);
#undef ARR
}

// Round 9
// 2193.835 us; speedup vs baseline: 1.2056x; 1.2056x over previous
//
#include <hip/hip_runtime.h>
#include <hip/hip_bf16.h>

// ---------------------------------------------------------------------------
// InvSlotAttentionGuide: CNN encoder -> pos embed -> MLP -> slot attention
// with MESH-Sinkhorn (manual reverse-mode through 5 sinkhorn iters).
// f32 end-to-end. R9: sa_kernel back to 512 threads (R8's 1024-thr was
// slower: barrier-latency-bound), fast transcendentals kept, and the
// backward pass restructured via LSE-reuse identities:
//   colLSE(u_t - C) = lb - v_t      (sigma denominators from history)
//   rowLSE(v_{t-1} - C) = la - u_t  (tau denominators from history)
// -> sigma+tau fused to one phase, init row+col merged, C+=gP and v5
// restore folded into t=1. ~450 -> ~310 barriers.
// ---------------------------------------------------------------------------

#define LN_EPS 1e-5f
#define SEPS 1e-8f
#define LN8 2.0794415416798357f

__device__ inline float wmaxall(float v) {
#pragma unroll
  for (int o = 32; o; o >>= 1) v = fmaxf(v, __shfl_down(v, o));
  return __shfl(v, 0);
}
__device__ inline float wsumall(float v) {
#pragma unroll
  for (int o = 32; o; o >>= 1) v += __shfl_down(v, o);
  return __shfl(v, 0);
}
__device__ inline int wsumi(int v) {
#pragma unroll
  for (int o = 32; o; o >>= 1) v += __shfl_down(v, o);
  return __shfl(v, 0);
}
__device__ inline float fast_sigmoid(float x) { return 1.f / (1.f + __expf(-x)); }
__device__ inline float fast_tanh(float x) { return 1.f - 2.f / (__expf(2.f * x) + 1.f); }

// ---------------------------------------------------------------------------
__global__ __launch_bounds__(64) void sniff_kernel(const unsigned int* __restrict__ img,
                                                   int* __restrict__ flag) {
  int cnt = 0;
  for (int i = threadIdx.x; i < 512; i += 64) {
    unsigned lo = img[i] & 0xFFFFu;
    int e = (int)((lo >> 7) & 0xFFu);
    cnt += (e >= 96 && e <= 140) ? 1 : 0;
  }
  cnt = wsumi(cnt);
  if (threadIdx.x == 0) *flag = (cnt >= 300) ? 1 : 0;
}

struct CvtArgs {
  const void* src[39];
  long off[40];
};

__global__ __launch_bounds__(256) void convert_kernel(CvtArgs a, const int* __restrict__ flag,
                                                      float* __restrict__ dst, long total) {
  const int isbf = *flag;
  for (long g = (long)blockIdx.x * 256 + threadIdx.x; g < total; g += (long)gridDim.x * 256) {
    int lo = 0, hi = 38;
    while (lo < hi) {
      int mid = (lo + hi + 1) >> 1;
      if (a.off[mid] <= g) lo = mid; else hi = mid - 1;
    }
    long li = g - a.off[lo];
    float v;
    if (isbf) v = __bfloat162float(((const __hip_bfloat16*)a.src[lo])[li]);
    else      v = ((const float*)a.src[lo])[li];
    dst[g] = v;
  }
}

// ---------------------------------------------------------------------------
struct TwArgs {
  long soff[9]; long doff[9]; int R[9]; int C[9];
};

__global__ __launch_bounds__(256) void transw_kernel(const float* __restrict__ cvt,
                                                     float* __restrict__ tws, TwArgs a) {
  int m = blockIdx.x;
  const float* S = cvt + a.soff[m];
  float* D = tws + a.doff[m];
  int R = a.R[m], C = a.C[m];
  for (int idx = threadIdx.x; idx < R * C; idx += 256) {
    int i = idx / C, j = idx - i * C;
    D[j * R + i] = S[idx];
  }
}

// ---------------------------------------------------------------------------
// Direct 5x5 conv + bias + relu (R7-verified): 16x16 tile, 16 oc/block,
// 2x2-px x 4-oc micro-tile, weights LDS-staged.
// ---------------------------------------------------------------------------
template <int S>
__global__ __launch_bounds__(256) void conv5x5(
    const float* __restrict__ in, const float* __restrict__ wgt,
    const float* __restrict__ bias, float* __restrict__ out,
    int Cin, int H, int W, int Wo, int Cout, int tilesX,
    int oybeg, int oyend, int ibase, int irows, int obase, int orows) {
  constexpr int P = 15 * S + 5;
  __shared__ float patch[P * P];
  __shared__ float wt[16 * 25];
  const int b = blockIdx.z;
  const int ocg = blockIdx.y * 16;
  const int ty0 = oybeg + (blockIdx.x / tilesX) * 16, tx0 = (blockIdx.x % tilesX) * 16;
  const int og = threadIdx.x >> 6;
  const int q = threadIdx.x & 63;
  const int qx = q & 7, qy = q >> 3;
  const int iy0 = ty0 * S - 2, ix0 = tx0 * S - 2;
  float acc[2][2][4];
#pragma unroll
  for (int dy = 0; dy < 2; dy++)
#pragma unroll
    for (int dx = 0; dx < 2; dx++)
#pragma unroll
      for (int j = 0; j < 4; j++) acc[dy][dx][j] = 0.f;

  for (int ci = 0; ci < Cin; ++ci) {
    const float* inp = in + ((long)b * Cin + ci) * (long)irows * W;
    for (int idx = threadIdx.x; idx < P * P; idx += 256) {
      int py = idx / P, px = idx - py * P;
      int iy = iy0 + py, ix = ix0 + px;
      float v = 0.f;
      if (iy >= 0 && iy < H && ix >= 0 && ix < W) v = inp[(long)(iy - ibase) * W + ix];
      patch[idx] = v;
    }
    for (int idx = threadIdx.x; idx < 16 * 25; idx += 256) {
      int j = idx / 25, tp = idx - j * 25;
      wt[idx] = wgt[((long)(ocg + j) * Cin + ci) * 25 + tp];
    }
    __syncthreads();
#pragma unroll
    for (int ky = 0; ky < 5; ky++) {
#pragma unroll
      for (int kx = 0; kx < 5; kx++) {
        const int wof = ky * 5 + kx;
        float w0 = wt[(og * 4 + 0) * 25 + wof];
        float w1 = wt[(og * 4 + 1) * 25 + wof];
        float w2 = wt[(og * 4 + 2) * 25 + wof];
        float w3 = wt[(og * 4 + 3) * 25 + wof];
#pragma unroll
        for (int dy = 0; dy < 2; dy++) {
#pragma unroll
          for (int dx = 0; dx < 2; dx++) {
            float iv = patch[((qy + 8 * dy) * S + ky) * P + (qx + 8 * dx) * S + kx];
            acc[dy][dx][0] += iv * w0;
            acc[dy][dx][1] += iv * w1;
            acc[dy][dx][2] += iv * w2;
            acc[dy][dx][3] += iv * w3;
          }
        }
      }
    }
    __syncthreads();
  }
#pragma unroll
  for (int dy = 0; dy < 2; dy++) {
    int oy = ty0 + qy + 8 * dy;
    if (oy >= oyend) continue;
#pragma unroll
    for (int dx = 0; dx < 2; dx++) {
      int ox = tx0 + qx + 8 * dx;
#pragma unroll
      for (int j = 0; j < 4; j++) {
        int oc = ocg + og * 4 + j;
        float r = fmaxf(acc[dy][dx][j] + bias[oc], 0.f);
        out[(((long)b * Cout + oc) * orows + (oy - obase)) * Wo + ox] = r;
      }
    }
  }
}

// ---------------------------------------------------------------------------
__global__ __launch_bounds__(256) void posembed_kernel(
    const float* __restrict__ act4, const float* __restrict__ pos_w,
    const float* __restrict__ pos_b, float* __restrict__ feat) {
  int idx = blockIdx.x * 256 + threadIdx.x;
  if (idx >= 16 * 1024 * 64) return;
  int c = idx & 63;
  int n = (idx >> 6) & 1023;
  int b = idx >> 16;
  int h = n >> 5, w = n & 31;
  float gh = h * (1.f / 31.f), gw = w * (1.f / 31.f);
  float e = gh * pos_w[c * 4 + 0] + gw * pos_w[c * 4 + 1] +
            (1.f - gh) * pos_w[c * 4 + 2] + (1.f - gw) * pos_w[c * 4 + 3] + pos_b[c];
  feat[idx] = act4[(((long)b * 64 + c) * 32 + h) * 32 + w] + e;
}

// ---------------------------------------------------------------------------
__global__ __launch_bounds__(64) void token_kernel(
    const float* __restrict__ feat,
    const float* __restrict__ mlp1T, const float* __restrict__ mlp1_b,
    const float* __restrict__ mlp2T, const float* __restrict__ mlp2_b,
    const float* __restrict__ lnin_w, const float* __restrict__ lnin_b,
    const float* __restrict__ wkT, const float* __restrict__ wvT,
    const float* __restrict__ mwi_w, const float* __restrict__ mwi_b,
    float* __restrict__ knT_out, float* __restrict__ v_out, float* __restrict__ lg_out) {
  const int t = blockIdx.x, i = threadIdx.x;
  const int b = t >> 10, nn = t & 1023;
  __shared__ float f[64], h1[64], inp[64];
  f[i] = feat[(long)t * 64 + i];
  __syncthreads();
  float acc = 0.f;
  for (int j = 0; j < 64; j++) acc += f[j] * mlp1T[j * 64 + i];
  h1[i] = fmaxf(acc + mlp1_b[i], 0.f);
  __syncthreads();
  acc = 0.f;
  for (int j = 0; j < 64; j++) acc += h1[j] * mlp2T[j * 64 + i];
  float x = acc + mlp2_b[i];
  float m = wsumall(x) * (1.f / 64.f);
  float d0 = x - m;
  float var = wsumall(d0 * d0) * (1.f / 64.f);
  float xin = d0 * rsqrtf(var + LN_EPS) * lnin_w[i] + lnin_b[i];
  inp[i] = xin;
  __syncthreads();
  float kv = 0.f, vv = 0.f;
  for (int j = 0; j < 64; j++) {
    float ij = inp[j];
    kv += ij * wkT[j * 64 + i];
    vv += ij * wvT[j * 64 + i];
  }
  float ss = wsumall(kv * kv);
  knT_out[(long)b * 65536 + i * 1024 + nn] = kv / fmaxf(sqrtf(ss), 1e-12f);
  v_out[(long)t * 64 + i] = vv;
  float lg = wsumall(xin * mwi_w[i]);
  if (i == 0) lg_out[t] = lg + mwi_b[0];
}

// ---------------------------------------------------------------------------
__global__ __launch_bounds__(256) void la_kernel(float* __restrict__ lg) {
  __shared__ float red[256];
  const int b = blockIdx.x, t = threadIdx.x;
  float* p = lg + b * 1024;
  float mx = -1e30f;
  for (int n = t; n < 1024; n += 256) mx = fmaxf(mx, p[n]);
  red[t] = mx;
  __syncthreads();
  for (int o = 128; o; o >>= 1) {
    if (t < o) red[t] = fmaxf(red[t], red[t + o]);
    __syncthreads();
  }
  float M = red[0];
  __syncthreads();
  float s = 0.f;
  for (int n = t; n < 1024; n += 256) s += __expf(p[n] - M);
  red[t] = s;
  __syncthreads();
  for (int o = 128; o; o >>= 1) {
    if (t < o) red[t] += red[t + o];
    __syncthreads();
  }
  float lse = M + __logf(red[0]);
  __syncthreads();
  for (int n = t; n < 1024; n += 256) p[n] = p[n] - lse + LN8;
}

// ---------------------------------------------------------------------------
// Slot-attention loop: 1 block/batch, 512 threads = 8 waves (wave s =
// column s in column phases; 2 rows/thread in row phases). gP, u-history,
// init-grads in registers. LSE-reuse identities kill backward recomputes.
// ---------------------------------------------------------------------------
__global__ __launch_bounds__(512) void sa_kernel(
    const float* __restrict__ knT_g, const float* __restrict__ v_g,
    const float* __restrict__ la_g, const float* __restrict__ noise,
    const float* __restrict__ mu_w, const float* __restrict__ sg_w,
    const float* __restrict__ lnsl_w, const float* __restrict__ lnsl_b,
    const float* __restrict__ mws_w, const float* __restrict__ mws_b,
    const float* __restrict__ wqT,
    const float* __restrict__ wihT, const float* __restrict__ whhT,
    const float* __restrict__ bih, const float* __restrict__ bhh,
    const float* __restrict__ lnff_w, const float* __restrict__ lnff_b,
    const float* __restrict__ fc1T, const float* __restrict__ fc1_b,
    const float* __restrict__ fc2T, const float* __restrict__ fc2_b,
    float* __restrict__ out) {
  const int b = blockIdx.x, tid = threadIdx.x;
  const int wv = tid >> 6, ln = tid & 63;

  __shared__ float sCt[8192];                                    // C^T (then pi^T)
  __shared__ float sLa[1024], sU[1024], sGu[1024], sRow[1024], sHid[1024];
  __shared__ float sVh[48], sV[8], sGv[8], sLb[8], sBm[8];
  __shared__ float sSlots[512], sNorm[512], sQn[512], sUpd[512];

  const float* knt = knT_g + (long)b * 65536;  // [64][1024]
  const float* vf = v_g + (long)b * 65536;     // [1024][64]
  float u_hist[5][2];   // u_t for my 2 rows
  float gPr[2][8];      // dC for my 2 rows
  float gInit[2];       // init row-grad sums

  {
    int dd = tid & 63;
    sSlots[tid] = mu_w[dd] + (fabsf(sg_w[dd]) + SEPS) * noise[(long)b * 512 + tid];
  }
  for (int n = tid; n < 1024; n += 512) sLa[n] = la_g[b * 1024 + n];
  __syncthreads();

  for (int it = 0; it < 3; ++it) {
    {  // slot LN + bm logit
      float x = sSlots[wv * 64 + ln];
      float m = wsumall(x) * (1.f / 64.f);
      float d0 = x - m;
      float var = wsumall(d0 * d0) * (1.f / 64.f);
      float xn = d0 * rsqrtf(var + LN_EPS) * lnsl_w[ln] + lnsl_b[ln];
      sNorm[wv * 64 + ln] = xn;
      float bmv = wsumall(xn * mws_w[ln]);
      if (ln == 0) sBm[wv] = bmv + mws_b[0];
    }
    __syncthreads();
    if (tid == 0) {  // lb = log(softmax(bm)*8)
      float mx = -1e30f;
      for (int s = 0; s < 8; s++) mx = fmaxf(mx, sBm[s]);
      float ss = 0.f;
      for (int s = 0; s < 8; s++) ss += __expf(sBm[s] - mx);
      float lse = mx + __logf(ss);
      for (int s = 0; s < 8; s++) sLb[s] = sBm[s] - lse + LN8;
    }
    {  // q = sNorm @ wq.T
      float acc = 0.f;
      for (int j = 0; j < 64; j++) acc += sNorm[wv * 64 + j] * wqT[j * 64 + ln];
      sQn[tid] = acc;
    }
    __syncthreads();
    {  // l2norm q
      float qv = sQn[wv * 64 + ln];
      float ss = wsumall(qv * qv);
      sQn[wv * 64 + ln] = qv / fmaxf(sqrtf(ss), 1e-12f);
    }
    if (tid < 8) sV[tid] = 0.f;
    __syncthreads();

#pragma unroll
    for (int k = 0; k < 2; k++) {  // C^T = 1 - qn.kn
      int n = tid + 512 * k;
      float acc[8];
#pragma unroll
      for (int s = 0; s < 8; s++) acc[s] = 0.f;
      for (int j = 0; j < 64; j++) {
        float kvv = knt[j * 1024 + n];
#pragma unroll
        for (int s = 0; s < 8; s++) acc[s] += kvv * sQn[s * 64 + j];
      }
#pragma unroll
      for (int s = 0; s < 8; s++) sCt[s * 1024 + n] = 1.f - acc[s];
    }
    __syncthreads();

    // --- MESH: 4 x (fwd 5 sinkhorn, fused backward, apply) ---
    for (int m = 0; m < 4; m++) {
#pragma unroll
      for (int t = 1; t <= 5; t++) {
        if (t == 1 && tid < 8) sVh[tid] = sV[tid];  // save v_0 (sV not written here)
#pragma unroll
        for (int k = 0; k < 2; k++) {  // row LSE -> u
          int n = tid + 512 * k;
          float mx = -1e30f;
#pragma unroll
          for (int s = 0; s < 8; s++) mx = fmaxf(mx, sV[s] - sCt[s * 1024 + n]);
          float ssum = 0.f;
#pragma unroll
          for (int s = 0; s < 8; s++) ssum += __expf(sV[s] - sCt[s * 1024 + n] - mx);
          float un = sLa[n] - (mx + __logf(ssum));
          sU[n] = un;
          u_hist[t - 1][k] = un;
        }
        __syncthreads();
        {  // col LSE -> v
          int s = wv;
          float mx = -1e30f;
          for (int n = ln; n < 1024; n += 64) mx = fmaxf(mx, sU[n] - sCt[s * 1024 + n]);
          mx = wmaxall(mx);
          float ssum = 0.f;
          for (int n = ln; n < 1024; n += 64) ssum += __expf(sU[n] - sCt[s * 1024 + n] - mx);
          ssum = wsumall(ssum);
          if (ln == 0) {
            float vs = sLb[s] - (mx + __logf(ssum));
            sV[s] = vs;
            sVh[t * 8 + s] = vs;
          }
        }
        __syncthreads();
      }
      {  // merged backward init: row entropy grads (regs) + col gv sums
#pragma unroll
        for (int k = 0; k < 2; k++) {
          int n = tid + 512 * k;
          float un = u_hist[4][k];
          float gul = 0.f;
#pragma unroll
          for (int s = 0; s < 8; s++) {
            float pi = __expf(un + sV[s] - sCt[s * 1024 + n]);
            float gl = -(__logf(pi + SEPS) + pi / (pi + SEPS)) * pi * (1.f / 16.f);
            gPr[k][s] = gl;
            gul += gl;
          }
          gInit[k] = gul;
        }
        {
          int s = wv;
          float vs = sV[s];
          float acc = 0.f;
          for (int n = ln; n < 1024; n += 64) {
            float pi = __expf(sU[n] + vs - sCt[s * 1024 + n]);
            acc += -(__logf(pi + SEPS) + pi / (pi + SEPS)) * pi * (1.f / 16.f);
          }
          acc = wsumall(acc);
          if (ln == 0) sGv[s] = acc;
        }
      }
      __syncthreads();
#pragma unroll
      for (int t = 5; t >= 1; t--) {
        {  // FUSED sigma+tau row pass; sCol = lb - v_t, rowLSE = la - u_t
#pragma unroll
          for (int k = 0; k < 2; k++) {
            int n = tid + 512 * k;
            float un = u_hist[t - 1][k];
            float gul = (t == 5) ? gInit[k] : 0.f;
#pragma unroll
            for (int s = 0; s < 8; s++) {
              float t2 = sGv[s] * __expf(un - sCt[s * 1024 + n] - (sLb[s] - sVh[t * 8 + s]));
              gPr[k][s] -= t2;
              gul -= t2;
            }
            float rowlse = sLa[n] - un;
#pragma unroll
            for (int s = 0; s < 8; s++)
              gPr[k][s] -= gul * __expf(sVh[(t - 1) * 8 + s] - sCt[s * 1024 + n] - rowlse);
            sGu[n] = gul;
            sRow[n] = rowlse;
            if (t == 1) {  // apply C += gP (row-local; gv phase skipped at t=1)
#pragma unroll
              for (int s = 0; s < 8; s++) sCt[s * 1024 + n] += gPr[k][s];
            }
          }
          if (t == 1 && tid < 8) sV[tid] = sVh[40 + tid];  // warm start v5 (sV unread here)
        }
        __syncthreads();
        if (t > 1) {  // gv for v_{t-1}
          int s = wv;
          float vvh = sVh[(t - 1) * 8 + s];
          float acc = 0.f;
          for (int n = ln; n < 1024; n += 64)
            acc += sGu[n] * __expf(vvh - sCt[s * 1024 + n] - sRow[n]);
          acc = wsumall(acc);
          if (ln == 0) sGv[s] = -acc;
          __syncthreads();
        }
      }
    }

    // --- final sinkhorn (5 iters, warm start v) ---
    for (int t = 0; t < 5; t++) {
#pragma unroll
      for (int k = 0; k < 2; k++) {
        int n = tid + 512 * k;
        float mx = -1e30f;
#pragma unroll
        for (int s = 0; s < 8; s++) mx = fmaxf(mx, sV[s] - sCt[s * 1024 + n]);
        float ssum = 0.f;
#pragma unroll
        for (int s = 0; s < 8; s++) ssum += __expf(sV[s] - sCt[s * 1024 + n] - mx);
        sU[n] = sLa[n] - (mx + __logf(ssum));
      }
      __syncthreads();
      {
        int s = wv;
        float mx = -1e30f;
        for (int n = ln; n < 1024; n += 64) mx = fmaxf(mx, sU[n] - sCt[s * 1024 + n]);
        mx = wmaxall(mx);
        float ssum = 0.f;
        for (int n = ln; n < 1024; n += 64) ssum += __expf(sU[n] - sCt[s * 1024 + n] - mx);
        ssum = wsumall(ssum);
        if (ln == 0) sV[s] = sLb[s] - (mx + __logf(ssum));
      }
      __syncthreads();
    }
#pragma unroll
    for (int k = 0; k < 2; k++) {  // pi^T in place of C^T
      int n = tid + 512 * k;
      float un = sU[n];
#pragma unroll
      for (int s = 0; s < 8; s++) sCt[s * 1024 + n] = __expf(un + sV[s] - sCt[s * 1024 + n]);
    }
    __syncthreads();
    if (it == 2) {
      for (int o = tid; o < 8192; o += 512) out[8192 + (long)b * 8192 + o] = sCt[o];
    }
    {  // updates[s,d] = sum_n pi[n,s]*v[n,d]
      int s = tid >> 6, dd = tid & 63;
      float acc = 0.f;
      for (int n = 0; n < 1024; n++) acc += sCt[s * 1024 + n] * vf[n * 64 + dd];
      sUpd[tid] = acc;
    }
    __syncthreads();
    // --- GRU ---
    float newslot;
    {
      int s = tid >> 6, i = tid & 63;
      const float* x = &sUpd[s * 64];
      const float* h = &sSlots[s * 64];
      float gir = 0, giz = 0, gin = 0, ghr = 0, ghz = 0, ghn = 0;
      for (int j = 0; j < 64; j++) {
        float xv = x[j], hv = h[j];
        gir += xv * wihT[j * 192 + i];
        giz += xv * wihT[j * 192 + 64 + i];
        gin += xv * wihT[j * 192 + 128 + i];
        ghr += hv * whhT[j * 192 + i];
        ghz += hv * whhT[j * 192 + 64 + i];
        ghn += hv * whhT[j * 192 + 128 + i];
      }
      gir += bih[i]; giz += bih[64 + i]; gin += bih[128 + i];
      ghr += bhh[i]; ghz += bhh[64 + i]; ghn += bhh[128 + i];
      float r = fast_sigmoid(gir + ghr);
      float z = fast_sigmoid(giz + ghz);
      float nn = fast_tanh(gin + r * ghn);
      newslot = (1.f - z) * nn + z * h[i];
    }
    __syncthreads();
    sSlots[tid] = newslot;
    __syncthreads();
    {  // ln_ff
      float x = sSlots[wv * 64 + ln];
      float m = wsumall(x) * (1.f / 64.f);
      float d0 = x - m;
      float var = wsumall(d0 * d0) * (1.f / 64.f);
      sNorm[wv * 64 + ln] = d0 * rsqrtf(var + LN_EPS) * lnff_w[ln] + lnff_b[ln];
    }
    __syncthreads();
    for (int o = tid; o < 1024; o += 512) {
      int s = o >> 7, k2 = o & 127;
      float acc = 0.f;
      for (int j = 0; j < 64; j++) acc += sNorm[s * 64 + j] * fc1T[j * 128 + k2];
      sHid[o] = fmaxf(acc + fc1_b[k2], 0.f);
    }
    __syncthreads();
    {
      int s = tid >> 6, i = tid & 63;
      float acc = 0.f;
      for (int j = 0; j < 128; j++) acc += sHid[s * 128 + j] * fc2T[j * 64 + i];
      newslot = sSlots[tid] + acc + fc2_b[i];
    }
    __syncthreads();
    sSlots[tid] = newslot;
    __syncthreads();
  }
  out[(long)b * 512 + tid] = sSlots[tid];
}

// ---------------------------------------------------------------------------
extern "C" void kernel_launch(void* const* d_in, const int* in_sizes, int n_in,
                              void* d_out, int out_size, void* d_ws, size_t ws_size,
                              hipStream_t stream) {
  (void)n_in; (void)out_size; (void)ws_size;
  char* ws = (char*)d_ws;
  float* cvt  = (float*)ws;                     // converted f32 inputs (4.7 MB)
  float* lgts = (float*)(ws + 5570560ull);
  float* band = (float*)(ws + 5636096ull);      // conv1 row-band (18.9 MB)
  float* act2 = (float*)(ws + 24510464ull);     // (16.8 MB)
  float* act3 = (float*)(ws + 5636096ull);      // over dead band
  float* act4 = (float*)(ws + 9830400ull);
  float* knT  = (float*)(ws + 9830400ull);      // over dead act4 (4 MB)
  float* vf   = (float*)(ws + 14024704ull);
  float* feat = (float*)(ws + 24510464ull);     // over dead act2
  int*   flag = (int*)(ws + 41287680ull);
  float* tws  = (float*)(ws + 41291776ull);     // transposed weights (240 KB)

  CvtArgs ca;
  long total = 0;
  for (int i = 0; i < 39; i++) { ca.src[i] = d_in[i]; ca.off[i] = total; total += in_sizes[i]; }
  ca.off[39] = total;

  sniff_kernel<<<1, 64, 0, stream>>>((const unsigned int*)d_in[0], flag);
  convert_kernel<<<1024, 256, 0, stream>>>(ca, flag, cvt, total);

#define ARR(i) (cvt + ca.off[i])
  TwArgs ta;
  {
    const int src[9] = {12, 14, 18, 19, 20, 27, 28, 33, 35};
    const int R[9] = {64, 64, 64, 64, 64, 192, 192, 128, 64};
    const int C[9] = {64, 64, 64, 64, 64, 64, 64, 64, 128};
    long d = 0;
    for (int m2 = 0; m2 < 9; m2++) {
      ta.soff[m2] = ca.off[src[m2]];
      ta.doff[m2] = d;
      ta.R[m2] = R[m2];
      ta.C[m2] = C[m2];
      d += (long)R[m2] * C[m2];
    }
  }
  transw_kernel<<<9, 256, 0, stream>>>(cvt, tws, ta);
  float* mlp1T = tws + 0,     *mlp2T = tws + 4096,  *wkT = tws + 8192, *wvT = tws + 12288;
  float* wqT   = tws + 16384, *wihT  = tws + 20480, *whhT = tws + 32768;
  float* fc1T  = tws + 45056, *fc2T  = tws + 53248;

  const float* image = ARR(0);
  const float* noise = ARR(1);

  for (int q = 0; q < 4; q++) {
    int obase = (q == 0) ? 0 : 32 * q - 2;
    int oyend1 = (q == 3) ? 128 : 32 * q + 34;
    conv5x5<1><<<dim3(24, 4, 16), 256, 0, stream>>>(
        image, ARR(2), ARR(3), band, 3, 128, 128, 128, 64, 8,
        obase, oyend1, 0, 128, obase, 36);
    conv5x5<2><<<dim3(4, 4, 16), 256, 0, stream>>>(
        band, ARR(4), ARR(5), act2, 64, 128, 128, 64, 64, 4,
        16 * q, 16 * q + 16, obase, 36, 0, 64);
  }
  conv5x5<2><<<dim3(4, 4, 16), 256, 0, stream>>>(
      act2, ARR(6), ARR(7), act3, 64, 64, 64, 32, 64, 2, 0, 32, 0, 64, 0, 32);
  conv5x5<1><<<dim3(4, 4, 16), 256, 0, stream>>>(
      act3, ARR(8), ARR(9), act4, 64, 32, 32, 32, 64, 2, 0, 32, 0, 32, 0, 32);

  posembed_kernel<<<4096, 256, 0, stream>>>(act4, ARR(10), ARR(11), feat);

  token_kernel<<<16384, 64, 0, stream>>>(feat, mlp1T, ARR(13), mlp2T, ARR(15),
                                         ARR(16), ARR(17), wkT, wvT, ARR(21), ARR(22),
                                         knT, vf, lgts);

  la_kernel<<<16, 256, 0, stream>>>(lgts);

  sa_kernel<<<16, 512, 0, stream>>>(knT, vf, lgts, noise, ARR(37), ARR(38),
                                    ARR(25), ARR(26), ARR(23), ARR(24), wqT,
                                    wihT, whhT, ARR(29), ARR(30),
                                    ARR(31), ARR(32), fc1T, ARR(34), fc2T, ARR(36),
                                    (float*)d_out);
#undef ARR
}

// Round 10
// 1315.716 us; speedup vs baseline: 2.0102x; 1.6674x over previous
//
#include <hip/hip_runtime.h>
#include <hip/hip_bf16.h>

// ---------------------------------------------------------------------------
// InvSlotAttentionGuide: CNN encoder -> pos embed -> MLP -> slot attention
// with MESH-Sinkhorn (manual reverse-mode through 5 sinkhorn iters).
// R10: convs restructured — conv1/conv2 un-sliced (act1/act2 stored bf16,
// one dispatch each, conv2 gets 1024 blocks), inner loop uses 4-px-run
// register windows (iv reads 100->55/ci) and wt[tap][16] b128 broadcast
// weight reads (100->25/ci). sa_kernel kept from R9 (543 us, verified).
// ---------------------------------------------------------------------------

#define LN_EPS 1e-5f
#define SEPS 1e-8f
#define LN8 2.0794415416798357f

__device__ inline float ldf(float x) { return x; }
__device__ inline float ldf(__hip_bfloat16 x) { return __bfloat162float(x); }
__device__ inline void stf(float* p, float v) { *p = v; }
__device__ inline void stf(__hip_bfloat16* p, float v) { *p = __float2bfloat16(v); }

__device__ inline float wmaxall(float v) {
#pragma unroll
  for (int o = 32; o; o >>= 1) v = fmaxf(v, __shfl_down(v, o));
  return __shfl(v, 0);
}
__device__ inline float wsumall(float v) {
#pragma unroll
  for (int o = 32; o; o >>= 1) v += __shfl_down(v, o);
  return __shfl(v, 0);
}
__device__ inline int wsumi(int v) {
#pragma unroll
  for (int o = 32; o; o >>= 1) v += __shfl_down(v, o);
  return __shfl(v, 0);
}
__device__ inline float fast_sigmoid(float x) { return 1.f / (1.f + __expf(-x)); }
__device__ inline float fast_tanh(float x) { return 1.f - 2.f / (__expf(2.f * x) + 1.f); }

// ---------------------------------------------------------------------------
__global__ __launch_bounds__(64) void sniff_kernel(const unsigned int* __restrict__ img,
                                                   int* __restrict__ flag) {
  int cnt = 0;
  for (int i = threadIdx.x; i < 512; i += 64) {
    unsigned lo = img[i] & 0xFFFFu;
    int e = (int)((lo >> 7) & 0xFFu);
    cnt += (e >= 96 && e <= 140) ? 1 : 0;
  }
  cnt = wsumi(cnt);
  if (threadIdx.x == 0) *flag = (cnt >= 300) ? 1 : 0;
}

struct CvtArgs {
  const void* src[39];
  long off[40];
};

__global__ __launch_bounds__(256) void convert_kernel(CvtArgs a, const int* __restrict__ flag,
                                                      float* __restrict__ dst, long total) {
  const int isbf = *flag;
  for (long g = (long)blockIdx.x * 256 + threadIdx.x; g < total; g += (long)gridDim.x * 256) {
    int lo = 0, hi = 38;
    while (lo < hi) {
      int mid = (lo + hi + 1) >> 1;
      if (a.off[mid] <= g) lo = mid; else hi = mid - 1;
    }
    long li = g - a.off[lo];
    float v;
    if (isbf) v = __bfloat162float(((const __hip_bfloat16*)a.src[lo])[li]);
    else      v = ((const float*)a.src[lo])[li];
    dst[g] = v;
  }
}

// ---------------------------------------------------------------------------
struct TwArgs {
  long soff[9]; long doff[9]; int R[9]; int C[9];
};

__global__ __launch_bounds__(256) void transw_kernel(const float* __restrict__ cvt,
                                                     float* __restrict__ tws, TwArgs a) {
  int m = blockIdx.x;
  const float* S = cvt + a.soff[m];
  float* D = tws + a.doff[m];
  int R = a.R[m], C = a.C[m];
  for (int idx = threadIdx.x; idx < R * C; idx += 256) {
    int i = idx / C, j = idx - i * C;
    D[j * R + i] = S[idx];
  }
}

// ---------------------------------------------------------------------------
// Direct 5x5 conv + bias + relu, pad=2. 16x16 tile x 16 oc per block,
// 256 threads: og=tid>>6 (4 oc), r=(tid>>2)&15 (row), rx=tid&3 (4-px run).
// Register iv window per (ky): 3S+5 values serve 4 px x 5 kx. Weights in
// LDS as [tap][16] -> one broadcast b128 per (tap, og).
// ---------------------------------------------------------------------------
template <int S, typename TIN, typename TOUT>
__global__ __launch_bounds__(256) void conv5x5(
    const TIN* __restrict__ in, const float* __restrict__ wgt,
    const float* __restrict__ bias, TOUT* __restrict__ out,
    int Cin, int H, int W, int Ho, int Wo, int Cout, int tilesX) {
  constexpr int P = 15 * S + 5;   // patch dim
  constexpr int WIN = 3 * S + 5;  // window width per 4-px run
  __shared__ float patch[P * P];
  __shared__ float wt16[25 * 16];
  const int b = blockIdx.z;
  const int ocg = blockIdx.y * 16;
  const int ty0 = (blockIdx.x / tilesX) * 16, tx0 = (blockIdx.x % tilesX) * 16;
  const int og = threadIdx.x >> 6;
  const int r = (threadIdx.x >> 2) & 15;
  const int rx = threadIdx.x & 3;
  const int iy0 = ty0 * S - 2, ix0 = tx0 * S - 2;
  float acc[4][4];  // [px][oc]
#pragma unroll
  for (int p = 0; p < 4; p++)
#pragma unroll
    for (int j = 0; j < 4; j++) acc[p][j] = 0.f;

  for (int ci = 0; ci < Cin; ++ci) {
    const TIN* inp = in + ((long)b * Cin + ci) * (long)H * W;
    for (int idx = threadIdx.x; idx < P * P; idx += 256) {
      int py = idx / P, px = idx - py * P;
      int iy = iy0 + py, ix = ix0 + px;
      float v = 0.f;
      if (iy >= 0 && iy < H && ix >= 0 && ix < W) v = ldf(inp[(long)iy * W + ix]);
      patch[idx] = v;
    }
    for (int idx = threadIdx.x; idx < 25 * 16; idx += 256) {
      int tap = idx >> 4, j = idx & 15;
      wt16[idx] = wgt[((long)(ocg + j) * Cin + ci) * 25 + tap];
    }
    __syncthreads();
#pragma unroll
    for (int ky = 0; ky < 5; ky++) {
      float win[WIN];
      const int prow = (r * S + ky) * P + rx * 4 * S;
#pragma unroll
      for (int w = 0; w < WIN; w++) win[w] = patch[prow + w];
#pragma unroll
      for (int kx = 0; kx < 5; kx++) {
        const float4 wv = *(const float4*)&wt16[(ky * 5 + kx) * 16 + og * 4];
#pragma unroll
        for (int p = 0; p < 4; p++) {
          float iv = win[p * S + kx];
          acc[p][0] += iv * wv.x;
          acc[p][1] += iv * wv.y;
          acc[p][2] += iv * wv.z;
          acc[p][3] += iv * wv.w;
        }
      }
    }
    __syncthreads();
  }
  const int oy = ty0 + r, ox0 = tx0 + rx * 4;
#pragma unroll
  for (int j = 0; j < 4; j++) {
    int oc = ocg + og * 4 + j;
    float bs = bias[oc];
    TOUT* op = &out[(((long)b * Cout + oc) * Ho + oy) * Wo + ox0];
#pragma unroll
    for (int p = 0; p < 4; p++) stf(&op[p], fmaxf(acc[p][j] + bs, 0.f));
  }
}

// ---------------------------------------------------------------------------
__global__ __launch_bounds__(256) void posembed_kernel(
    const float* __restrict__ act4, const float* __restrict__ pos_w,
    const float* __restrict__ pos_b, float* __restrict__ feat) {
  int idx = blockIdx.x * 256 + threadIdx.x;
  if (idx >= 16 * 1024 * 64) return;
  int c = idx & 63;
  int n = (idx >> 6) & 1023;
  int b = idx >> 16;
  int h = n >> 5, w = n & 31;
  float gh = h * (1.f / 31.f), gw = w * (1.f / 31.f);
  float e = gh * pos_w[c * 4 + 0] + gw * pos_w[c * 4 + 1] +
            (1.f - gh) * pos_w[c * 4 + 2] + (1.f - gw) * pos_w[c * 4 + 3] + pos_b[c];
  feat[idx] = act4[(((long)b * 64 + c) * 32 + h) * 32 + w] + e;
}

// ---------------------------------------------------------------------------
__global__ __launch_bounds__(64) void token_kernel(
    const float* __restrict__ feat,
    const float* __restrict__ mlp1T, const float* __restrict__ mlp1_b,
    const float* __restrict__ mlp2T, const float* __restrict__ mlp2_b,
    const float* __restrict__ lnin_w, const float* __restrict__ lnin_b,
    const float* __restrict__ wkT, const float* __restrict__ wvT,
    const float* __restrict__ mwi_w, const float* __restrict__ mwi_b,
    float* __restrict__ knT_out, float* __restrict__ v_out, float* __restrict__ lg_out) {
  const int t = blockIdx.x, i = threadIdx.x;
  const int b = t >> 10, nn = t & 1023;
  __shared__ float f[64], h1[64], inp[64];
  f[i] = feat[(long)t * 64 + i];
  __syncthreads();
  float acc = 0.f;
  for (int j = 0; j < 64; j++) acc += f[j] * mlp1T[j * 64 + i];
  h1[i] = fmaxf(acc + mlp1_b[i], 0.f);
  __syncthreads();
  acc = 0.f;
  for (int j = 0; j < 64; j++) acc += h1[j] * mlp2T[j * 64 + i];
  float x = acc + mlp2_b[i];
  float m = wsumall(x) * (1.f / 64.f);
  float d0 = x - m;
  float var = wsumall(d0 * d0) * (1.f / 64.f);
  float xin = d0 * rsqrtf(var + LN_EPS) * lnin_w[i] + lnin_b[i];
  inp[i] = xin;
  __syncthreads();
  float kv = 0.f, vv = 0.f;
  for (int j = 0; j < 64; j++) {
    float ij = inp[j];
    kv += ij * wkT[j * 64 + i];
    vv += ij * wvT[j * 64 + i];
  }
  float ss = wsumall(kv * kv);
  knT_out[(long)b * 65536 + i * 1024 + nn] = kv / fmaxf(sqrtf(ss), 1e-12f);
  v_out[(long)t * 64 + i] = vv;
  float lg = wsumall(xin * mwi_w[i]);
  if (i == 0) lg_out[t] = lg + mwi_b[0];
}

// ---------------------------------------------------------------------------
__global__ __launch_bounds__(256) void la_kernel(float* __restrict__ lg) {
  __shared__ float red[256];
  const int b = blockIdx.x, t = threadIdx.x;
  float* p = lg + b * 1024;
  float mx = -1e30f;
  for (int n = t; n < 1024; n += 256) mx = fmaxf(mx, p[n]);
  red[t] = mx;
  __syncthreads();
  for (int o = 128; o; o >>= 1) {
    if (t < o) red[t] = fmaxf(red[t], red[t + o]);
    __syncthreads();
  }
  float M = red[0];
  __syncthreads();
  float s = 0.f;
  for (int n = t; n < 1024; n += 256) s += __expf(p[n] - M);
  red[t] = s;
  __syncthreads();
  for (int o = 128; o; o >>= 1) {
    if (t < o) red[t] += red[t + o];
    __syncthreads();
  }
  float lse = M + __logf(red[0]);
  __syncthreads();
  for (int n = t; n < 1024; n += 256) p[n] = p[n] - lse + LN8;
}

// ---------------------------------------------------------------------------
// Slot-attention loop (R9-verified): 512 threads, LSE-reuse fused backward.
// ---------------------------------------------------------------------------
__global__ __launch_bounds__(512) void sa_kernel(
    const float* __restrict__ knT_g, const float* __restrict__ v_g,
    const float* __restrict__ la_g, const float* __restrict__ noise,
    const float* __restrict__ mu_w, const float* __restrict__ sg_w,
    const float* __restrict__ lnsl_w, const float* __restrict__ lnsl_b,
    const float* __restrict__ mws_w, const float* __restrict__ mws_b,
    const float* __restrict__ wqT,
    const float* __restrict__ wihT, const float* __restrict__ whhT,
    const float* __restrict__ bih, const float* __restrict__ bhh,
    const float* __restrict__ lnff_w, const float* __restrict__ lnff_b,
    const float* __restrict__ fc1T, const float* __restrict__ fc1_b,
    const float* __restrict__ fc2T, const float* __restrict__ fc2_b,
    float* __restrict__ out) {
  const int b = blockIdx.x, tid = threadIdx.x;
  const int wv = tid >> 6, ln = tid & 63;

  __shared__ float sCt[8192];
  __shared__ float sLa[1024], sU[1024], sGu[1024], sRow[1024], sHid[1024];
  __shared__ float sVh[48], sV[8], sGv[8], sLb[8], sBm[8];
  __shared__ float sSlots[512], sNorm[512], sQn[512], sUpd[512];

  const float* knt = knT_g + (long)b * 65536;
  const float* vf = v_g + (long)b * 65536;
  float u_hist[5][2];
  float gPr[2][8];
  float gInit[2];

  {
    int dd = tid & 63;
    sSlots[tid] = mu_w[dd] + (fabsf(sg_w[dd]) + SEPS) * noise[(long)b * 512 + tid];
  }
  for (int n = tid; n < 1024; n += 512) sLa[n] = la_g[b * 1024 + n];
  __syncthreads();

  for (int it = 0; it < 3; ++it) {
    {
      float x = sSlots[wv * 64 + ln];
      float m = wsumall(x) * (1.f / 64.f);
      float d0 = x - m;
      float var = wsumall(d0 * d0) * (1.f / 64.f);
      float xn = d0 * rsqrtf(var + LN_EPS) * lnsl_w[ln] + lnsl_b[ln];
      sNorm[wv * 64 + ln] = xn;
      float bmv = wsumall(xn * mws_w[ln]);
      if (ln == 0) sBm[wv] = bmv + mws_b[0];
    }
    __syncthreads();
    if (tid == 0) {
      float mx = -1e30f;
      for (int s = 0; s < 8; s++) mx = fmaxf(mx, sBm[s]);
      float ss = 0.f;
      for (int s = 0; s < 8; s++) ss += __expf(sBm[s] - mx);
      float lse = mx + __logf(ss);
      for (int s = 0; s < 8; s++) sLb[s] = sBm[s] - lse + LN8;
    }
    {
      float acc = 0.f;
      for (int j = 0; j < 64; j++) acc += sNorm[wv * 64 + j] * wqT[j * 64 + ln];
      sQn[tid] = acc;
    }
    __syncthreads();
    {
      float qv = sQn[wv * 64 + ln];
      float ss = wsumall(qv * qv);
      sQn[wv * 64 + ln] = qv / fmaxf(sqrtf(ss), 1e-12f);
    }
    if (tid < 8) sV[tid] = 0.f;
    __syncthreads();

#pragma unroll
    for (int k = 0; k < 2; k++) {
      int n = tid + 512 * k;
      float acc[8];
#pragma unroll
      for (int s = 0; s < 8; s++) acc[s] = 0.f;
      for (int j = 0; j < 64; j++) {
        float kvv = knt[j * 1024 + n];
#pragma unroll
        for (int s = 0; s < 8; s++) acc[s] += kvv * sQn[s * 64 + j];
      }
#pragma unroll
      for (int s = 0; s < 8; s++) sCt[s * 1024 + n] = 1.f - acc[s];
    }
    __syncthreads();

    for (int m = 0; m < 4; m++) {
#pragma unroll
      for (int t = 1; t <= 5; t++) {
        if (t == 1 && tid < 8) sVh[tid] = sV[tid];
#pragma unroll
        for (int k = 0; k < 2; k++) {
          int n = tid + 512 * k;
          float mx = -1e30f;
#pragma unroll
          for (int s = 0; s < 8; s++) mx = fmaxf(mx, sV[s] - sCt[s * 1024 + n]);
          float ssum = 0.f;
#pragma unroll
          for (int s = 0; s < 8; s++) ssum += __expf(sV[s] - sCt[s * 1024 + n] - mx);
          float un = sLa[n] - (mx + __logf(ssum));
          sU[n] = un;
          u_hist[t - 1][k] = un;
        }
        __syncthreads();
        {
          int s = wv;
          float mx = -1e30f;
          for (int n = ln; n < 1024; n += 64) mx = fmaxf(mx, sU[n] - sCt[s * 1024 + n]);
          mx = wmaxall(mx);
          float ssum = 0.f;
          for (int n = ln; n < 1024; n += 64) ssum += __expf(sU[n] - sCt[s * 1024 + n] - mx);
          ssum = wsumall(ssum);
          if (ln == 0) {
            float vs = sLb[s] - (mx + __logf(ssum));
            sV[s] = vs;
            sVh[t * 8 + s] = vs;
          }
        }
        __syncthreads();
      }
      {
#pragma unroll
        for (int k = 0; k < 2; k++) {
          int n = tid + 512 * k;
          float un = u_hist[4][k];
          float gul = 0.f;
#pragma unroll
          for (int s = 0; s < 8; s++) {
            float pi = __expf(un + sV[s] - sCt[s * 1024 + n]);
            float gl = -(__logf(pi + SEPS) + pi / (pi + SEPS)) * pi * (1.f / 16.f);
            gPr[k][s] = gl;
            gul += gl;
          }
          gInit[k] = gul;
        }
        {
          int s = wv;
          float vs = sV[s];
          float acc = 0.f;
          for (int n = ln; n < 1024; n += 64) {
            float pi = __expf(sU[n] + vs - sCt[s * 1024 + n]);
            acc += -(__logf(pi + SEPS) + pi / (pi + SEPS)) * pi * (1.f / 16.f);
          }
          acc = wsumall(acc);
          if (ln == 0) sGv[s] = acc;
        }
      }
      __syncthreads();
#pragma unroll
      for (int t = 5; t >= 1; t--) {
        {
#pragma unroll
          for (int k = 0; k < 2; k++) {
            int n = tid + 512 * k;
            float un = u_hist[t - 1][k];
            float gul = (t == 5) ? gInit[k] : 0.f;
#pragma unroll
            for (int s = 0; s < 8; s++) {
              float t2 = sGv[s] * __expf(un - sCt[s * 1024 + n] - (sLb[s] - sVh[t * 8 + s]));
              gPr[k][s] -= t2;
              gul -= t2;
            }
            float rowlse = sLa[n] - un;
#pragma unroll
            for (int s = 0; s < 8; s++)
              gPr[k][s] -= gul * __expf(sVh[(t - 1) * 8 + s] - sCt[s * 1024 + n] - rowlse);
            sGu[n] = gul;
            sRow[n] = rowlse;
            if (t == 1) {
#pragma unroll
              for (int s = 0; s < 8; s++) sCt[s * 1024 + n] += gPr[k][s];
            }
          }
          if (t == 1 && tid < 8) sV[tid] = sVh[40 + tid];
        }
        __syncthreads();
        if (t > 1) {
          int s = wv;
          float vvh = sVh[(t - 1) * 8 + s];
          float acc = 0.f;
          for (int n = ln; n < 1024; n += 64)
            acc += sGu[n] * __expf(vvh - sCt[s * 1024 + n] - sRow[n]);
          acc = wsumall(acc);
          if (ln == 0) sGv[s] = -acc;
          __syncthreads();
        }
      }
    }

    for (int t = 0; t < 5; t++) {
#pragma unroll
      for (int k = 0; k < 2; k++) {
        int n = tid + 512 * k;
        float mx = -1e30f;
#pragma unroll
        for (int s = 0; s < 8; s++) mx = fmaxf(mx, sV[s] - sCt[s * 1024 + n]);
        float ssum = 0.f;
#pragma unroll
        for (int s = 0; s < 8; s++) ssum += __expf(sV[s] - sCt[s * 1024 + n] - mx);
        sU[n] = sLa[n] - (mx + __logf(ssum));
      }
      __syncthreads();
      {
        int s = wv;
        float mx = -1e30f;
        for (int n = ln; n < 1024; n += 64) mx = fmaxf(mx, sU[n] - sCt[s * 1024 + n]);
        mx = wmaxall(mx);
        float ssum = 0.f;
        for (int n = ln; n < 1024; n += 64) ssum += __expf(sU[n] - sCt[s * 1024 + n] - mx);
        ssum = wsumall(ssum);
        if (ln == 0) sV[s] = sLb[s] - (mx + __logf(ssum));
      }
      __syncthreads();
    }
#pragma unroll
    for (int k = 0; k < 2; k++) {
      int n = tid + 512 * k;
      float un = sU[n];
#pragma unroll
      for (int s = 0; s < 8; s++) sCt[s * 1024 + n] = __expf(un + sV[s] - sCt[s * 1024 + n]);
    }
    __syncthreads();
    if (it == 2) {
      for (int o = tid; o < 8192; o += 512) out[8192 + (long)b * 8192 + o] = sCt[o];
    }
    {
      int s = tid >> 6, dd = tid & 63;
      float acc = 0.f;
      for (int n = 0; n < 1024; n++) acc += sCt[s * 1024 + n] * vf[n * 64 + dd];
      sUpd[tid] = acc;
    }
    __syncthreads();
    float newslot;
    {
      int s = tid >> 6, i = tid & 63;
      const float* x = &sUpd[s * 64];
      const float* h = &sSlots[s * 64];
      float gir = 0, giz = 0, gin = 0, ghr = 0, ghz = 0, ghn = 0;
      for (int j = 0; j < 64; j++) {
        float xv = x[j], hv = h[j];
        gir += xv * wihT[j * 192 + i];
        giz += xv * wihT[j * 192 + 64 + i];
        gin += xv * wihT[j * 192 + 128 + i];
        ghr += hv * whhT[j * 192 + i];
        ghz += hv * whhT[j * 192 + 64 + i];
        ghn += hv * whhT[j * 192 + 128 + i];
      }
      gir += bih[i]; giz += bih[64 + i]; gin += bih[128 + i];
      ghr += bhh[i]; ghz += bhh[64 + i]; ghn += bhh[128 + i];
      float r = fast_sigmoid(gir + ghr);
      float z = fast_sigmoid(giz + ghz);
      float nn = fast_tanh(gin + r * ghn);
      newslot = (1.f - z) * nn + z * h[i];
    }
    __syncthreads();
    sSlots[tid] = newslot;
    __syncthreads();
    {
      float x = sSlots[wv * 64 + ln];
      float m = wsumall(x) * (1.f / 64.f);
      float d0 = x - m;
      float var = wsumall(d0 * d0) * (1.f / 64.f);
      sNorm[wv * 64 + ln] = d0 * rsqrtf(var + LN_EPS) * lnff_w[ln] + lnff_b[ln];
    }
    __syncthreads();
    for (int o = tid; o < 1024; o += 512) {
      int s = o >> 7, k2 = o & 127;
      float acc = 0.f;
      for (int j = 0; j < 64; j++) acc += sNorm[s * 64 + j] * fc1T[j * 128 + k2];
      sHid[o] = fmaxf(acc + fc1_b[k2], 0.f);
    }
    __syncthreads();
    {
      int s = tid >> 6, i = tid & 63;
      float acc = 0.f;
      for (int j = 0; j < 128; j++) acc += sHid[s * 128 + j] * fc2T[j * 64 + i];
      newslot = sSlots[tid] + acc + fc2_b[i];
    }
    __syncthreads();
    sSlots[tid] = newslot;
    __syncthreads();
  }
  out[(long)b * 512 + tid] = sSlots[tid];
}

// ---------------------------------------------------------------------------
extern "C" void kernel_launch(void* const* d_in, const int* in_sizes, int n_in,
                              void* d_out, int out_size, void* d_ws, size_t ws_size,
                              hipStream_t stream) {
  (void)n_in; (void)out_size; (void)ws_size;
  char* ws = (char*)d_ws;
  // Layout (peak ~47.9 MB; region up to 50.8 MB proven in-bounds in R2):
  float* cvt  = (float*)ws;                            // f32 inputs (4.7 MB)
  float* lgts = (float*)(ws + 5570560ull);
  __hip_bfloat16* act1 = (__hip_bfloat16*)(ws + 5636096ull);   // [16,64,128,128] bf16 33.55MB
  __hip_bfloat16* act2 = (__hip_bfloat16*)(ws + 39190528ull);  // [16,64,64,64]  bf16  8.39MB
  float* act3 = (float*)(ws + 5636096ull);             // over dead act1
  float* act4 = (float*)(ws + 9830400ull);
  float* knT  = (float*)(ws + 9830400ull);             // over dead act4
  float* vf   = (float*)(ws + 14024704ull);            // dead act1 region
  float* feat = (float*)(ws + 24510464ull);            // dead act1 region
  int*   flag = (int*)(ws + 47579136ull);
  float* tws  = (float*)(ws + 47583232ull);            // transposed weights (240 KB)

  CvtArgs ca;
  long total = 0;
  for (int i = 0; i < 39; i++) { ca.src[i] = d_in[i]; ca.off[i] = total; total += in_sizes[i]; }
  ca.off[39] = total;

  sniff_kernel<<<1, 64, 0, stream>>>((const unsigned int*)d_in[0], flag);
  convert_kernel<<<1024, 256, 0, stream>>>(ca, flag, cvt, total);

#define ARR(i) (cvt + ca.off[i])
  TwArgs ta;
  {
    const int src[9] = {12, 14, 18, 19, 20, 27, 28, 33, 35};
    const int R[9] = {64, 64, 64, 64, 64, 192, 192, 128, 64};
    const int C[9] = {64, 64, 64, 64, 64, 64, 64, 64, 128};
    long d = 0;
    for (int m2 = 0; m2 < 9; m2++) {
      ta.soff[m2] = ca.off[src[m2]];
      ta.doff[m2] = d;
      ta.R[m2] = R[m2];
      ta.C[m2] = C[m2];
      d += (long)R[m2] * C[m2];
    }
  }
  transw_kernel<<<9, 256, 0, stream>>>(cvt, tws, ta);
  float* mlp1T = tws + 0,     *mlp2T = tws + 4096,  *wkT = tws + 8192, *wvT = tws + 12288;
  float* wqT   = tws + 16384, *wihT  = tws + 20480, *whhT = tws + 32768;
  float* fc1T  = tws + 45056, *fc2T  = tws + 53248;

  const float* image = ARR(0);
  const float* noise = ARR(1);

  conv5x5<1, float, __hip_bfloat16><<<dim3(64, 4, 16), 256, 0, stream>>>(
      image, ARR(2), ARR(3), act1, 3, 128, 128, 128, 128, 64, 8);
  conv5x5<2, __hip_bfloat16, __hip_bfloat16><<<dim3(16, 4, 16), 256, 0, stream>>>(
      act1, ARR(4), ARR(5), act2, 64, 128, 128, 64, 64, 64, 4);
  conv5x5<2, __hip_bfloat16, float><<<dim3(4, 4, 16), 256, 0, stream>>>(
      act2, ARR(6), ARR(7), act3, 64, 64, 64, 32, 32, 64, 2);
  conv5x5<1, float, float><<<dim3(4, 4, 16), 256, 0, stream>>>(
      act3, ARR(8), ARR(9), act4, 64, 32, 32, 32, 32, 64, 2);

  posembed_kernel<<<4096, 256, 0, stream>>>(act4, ARR(10), ARR(11), feat);

  token_kernel<<<16384, 64, 0, stream>>>(feat, mlp1T, ARR(13), mlp2T, ARR(15),
                                         ARR(16), ARR(17), wkT, wvT, ARR(21), ARR(22),
                                         knT, vf, lgts);

  la_kernel<<<16, 256, 0, stream>>>(lgts);

  sa_kernel<<<16, 512, 0, stream>>>(knT, vf, lgts, noise, ARR(37), ARR(38),
                                    ARR(25), ARR(26), ARR(23), ARR(24), wqT,
                                    wihT, whhT, ARR(29), ARR(30),
                                    ARR(31), ARR(32), fc1T, ARR(34), fc2T, ARR(36),
                                    (float*)d_out);
#undef ARR
}